// Round 14
// baseline (704.562 us; speedup 1.0000x reference)
//
#include <hip/hip_runtime.h>
#include <hip/hip_bf16.h>

#define C_DIM 128
#define N_WIN 98
#define M_TOK 200704   // 8*8*56*56
#define B_WIN 2048

struct __align__(8) bf16x4 { __hip_bfloat16 h[4]; };

typedef __attribute__((ext_vector_type(8))) short bf16x8_t;   // 8 bf16 = 4 VGPRs
typedef __attribute__((ext_vector_type(4))) float f32x4_t;

// NOTE (R13 measured): tanh-form fast GELU (__expf + __fdividef) is SLOWER than
// libm erff here (171 -> 194us, VALUBusy 33 -> 39%). Quarter-rate transcendentals
// schedule worse than erff's full-rate FMA polynomial. Keep erff.

// token index map used by BOTH gather (LN1) and scatter (proj epilogue):
// row = widx*98 + n  ->  flat spatial token index in the original layout
__device__ __forceinline__ int token_spatial_index(int row) {
    int widx = row / 98;
    int n = row - widx * 98;
    int b   = widx >> 8;          // / 256
    int rem = widx & 255;
    int dI = rem >> 6;            // D/2 = 4
    int hI = (rem >> 3) & 7;      // H/7 = 8
    int wI = rem & 7;             // W/7 = 8
    int dw = n / 49;
    int r49 = n - dw * 49;
    int hw = r49 / 7;
    int ww = r49 - hw * 7;
    int d = dI * 2 + dw;          // shifted-frame coords
    int h = hI * 7 + hw;
    int w = wI * 7 + ww;
    d = (d + 1) & 7;              // shifted[i] = orig[(i+1)%8]  (roll -1)
    h += 3; if (h >= 56) h -= 56; // roll -3
    w += 3; if (w >= 56) w -= 56;
    return ((b * 8 + d) * 56 + h) * 56 + w;
}

// ---------------- Kernel 0: convert qkv_w + proj_w fp32 -> bf16 (into d_out head) ----------------
__global__ __launch_bounds__(256) void prep_qp_weights(
    const float* __restrict__ qkv_w,    // (384,128) = 49152
    const float* __restrict__ proj_w,   // (128,128) = 16384
    __hip_bfloat16* __restrict__ qp)    // [0..49151]=qkv_w, [49152..65535]=proj_w
{
    int i = blockIdx.x * 256 + threadIdx.x;
    if (i < 49152)      qp[i] = __float2bfloat16(qkv_w[i]);
    else if (i < 65536) qp[i] = __float2bfloat16(proj_w[i - 49152]);
}

// ---------------- Kernel 1: LN1 + window gather + QKV GEMM (bf16 MFMA, v2) ----------------
__global__ __launch_bounds__(256, 3) void ln1_qkv_kernel(
    const float* __restrict__ x,
    const float* __restrict__ g1,
    const float* __restrict__ b1,
    const __hip_bfloat16* __restrict__ qkv_wb,  // (384,128) bf16 (pre-converted)
    const float* __restrict__ qkv_b,            // (384,)
    __hip_bfloat16* __restrict__ qkv_out)       // (200704,384) bf16 scratch
{
    __shared__ __align__(16) __hip_bfloat16 Abf[64][136];   // 17408 B LN output
    __shared__ int srcL[64];

    const int tid  = threadIdx.x;
    const int lane = tid & 63;
    const int wv   = tid >> 6;
    const int rowbase = blockIdx.x * 64;

    if (tid < 64) srcL[tid] = token_spatial_index(rowbase + tid);
    __syncthreads();

    // ---- gather + LayerNorm, fully in registers ----
    {
        int r = tid >> 2, part = tid & 3;            // 4 lanes per row, 32 elems each
        const float* xp = x + (size_t)srcL[r] * 128 + part * 32;
        float v[32];
        float s = 0.f, ss = 0.f;
        #pragma unroll
        for (int j = 0; j < 8; ++j) {
            float4 f = *(const float4*)(xp + j * 4);
            v[j*4+0] = f.x; v[j*4+1] = f.y; v[j*4+2] = f.z; v[j*4+3] = f.w;
            s  += f.x + f.y + f.z + f.w;
            ss += f.x*f.x + f.y*f.y + f.z*f.z + f.w*f.w;
        }
        s += __shfl_xor(s, 1); ss += __shfl_xor(ss, 1);
        s += __shfl_xor(s, 2); ss += __shfl_xor(ss, 2);
        float m = s * (1.f / 128.f);
        float var = ss * (1.f / 128.f) - m * m;
        float rstd = rsqrtf(var + 1e-5f);
        #pragma unroll
        for (int j = 0; j < 8; ++j) {
            int k = part * 32 + j * 4;
            bf16x4 pk;
            pk.h[0] = __float2bfloat16((v[j*4+0] - m) * rstd * g1[k+0] + b1[k+0]);
            pk.h[1] = __float2bfloat16((v[j*4+1] - m) * rstd * g1[k+1] + b1[k+1]);
            pk.h[2] = __float2bfloat16((v[j*4+2] - m) * rstd * g1[k+2] + b1[k+2]);
            pk.h[3] = __float2bfloat16((v[j*4+3] - m) * rstd * g1[k+3] + b1[k+3]);
            *(bf16x4*)(&Abf[r][k]) = pk;
        }
    }
    __syncthreads();

    const int lm   = lane & 15;
    const int quad = lane >> 4;
    const int colbase = wv * 96;    // wave owns 96 of 384 out cols

    // activation fragments: all 4 row-tiles (B-operand)
    bf16x8_t afr[4][4];
    #pragma unroll
    for (int rt = 0; rt < 4; ++rt)
        #pragma unroll
        for (int s = 0; s < 4; ++s)
            afr[rt][s] = *(const bf16x8_t*)(&Abf[rt * 16 + lm][s * 32 + quad * 8]);

    #pragma unroll
    for (int ctb = 0; ctb < 3; ++ctb) {
        // batch-load 8 weight fragments (2 col-tiles x 4 K-slices), A-operand
        bf16x8_t wfr[2][4];
        #pragma unroll
        for (int cti = 0; cti < 2; ++cti) {
            int wcol = colbase + (ctb * 2 + cti) * 16 + lm;        // A-row = out col
            const __hip_bfloat16* wp = qkv_wb + (size_t)wcol * 128 + quad * 8;
            #pragma unroll
            for (int s = 0; s < 4; ++s)
                wfr[cti][s] = *(const bf16x8_t*)(wp + s * 32);
        }
        #pragma unroll
        for (int cti = 0; cti < 2; ++cti) {
            int gcol4 = colbase + (ctb * 2 + cti) * 16 + quad * 4; // lane's 4 out cols
            float4 fb = *(const float4*)(qkv_b + gcol4);
            f32x4_t a0 = {0.f,0.f,0.f,0.f}, a1 = {0.f,0.f,0.f,0.f};
            f32x4_t a2 = {0.f,0.f,0.f,0.f}, a3 = {0.f,0.f,0.f,0.f};
            #pragma unroll
            for (int s = 0; s < 4; ++s) {
                a0 = __builtin_amdgcn_mfma_f32_16x16x32_bf16(wfr[cti][s], afr[0][s], a0, 0, 0, 0);
                a1 = __builtin_amdgcn_mfma_f32_16x16x32_bf16(wfr[cti][s], afr[1][s], a1, 0, 0, 0);
                a2 = __builtin_amdgcn_mfma_f32_16x16x32_bf16(wfr[cti][s], afr[2][s], a2, 0, 0, 0);
                a3 = __builtin_amdgcn_mfma_f32_16x16x32_bf16(wfr[cti][s], afr[3][s], a3, 0, 0, 0);
            }
            // lane: token row rt*16+lm, out cols gcol4..gcol4+3 -> packed bf16x4 store
            bf16x4 pk;
            pk.h[0] = __float2bfloat16(a0[0] + fb.x);
            pk.h[1] = __float2bfloat16(a0[1] + fb.y);
            pk.h[2] = __float2bfloat16(a0[2] + fb.z);
            pk.h[3] = __float2bfloat16(a0[3] + fb.w);
            *(bf16x4*)(qkv_out + (size_t)(rowbase +  0 + lm) * 384 + gcol4) = pk;
            pk.h[0] = __float2bfloat16(a1[0] + fb.x);
            pk.h[1] = __float2bfloat16(a1[1] + fb.y);
            pk.h[2] = __float2bfloat16(a1[2] + fb.z);
            pk.h[3] = __float2bfloat16(a1[3] + fb.w);
            *(bf16x4*)(qkv_out + (size_t)(rowbase + 16 + lm) * 384 + gcol4) = pk;
            pk.h[0] = __float2bfloat16(a2[0] + fb.x);
            pk.h[1] = __float2bfloat16(a2[1] + fb.y);
            pk.h[2] = __float2bfloat16(a2[2] + fb.z);
            pk.h[3] = __float2bfloat16(a2[3] + fb.w);
            *(bf16x4*)(qkv_out + (size_t)(rowbase + 32 + lm) * 384 + gcol4) = pk;
            pk.h[0] = __float2bfloat16(a3[0] + fb.x);
            pk.h[1] = __float2bfloat16(a3[1] + fb.y);
            pk.h[2] = __float2bfloat16(a3[2] + fb.z);
            pk.h[3] = __float2bfloat16(a3[3] + fb.w);
            *(bf16x4*)(qkv_out + (size_t)(rowbase + 48 + lm) * 384 + gcol4) = pk;
        }
    }
}

// ---------------- Kernel 2: attention per (window, head), MFMA (v2, unchanged) ----------------
#define SWZ(r, c) (((r) * 128) + ((c) ^ (((r) & 7) << 3)))

__global__ __launch_bounds__(256) void attn_mfma_kernel(
    __hip_bfloat16* __restrict__ qkv,           // (200704,384); out overwrites q-slice
    const float* __restrict__ rel_bias)         // (507,4)
{
    __shared__ __align__(16) __hip_bfloat16 Kb[112][40];    // 8960 B (rows padded w/ zeros)
    __shared__ __align__(16) __hip_bfloat16 Vt[32 * 128];   // 8192 B swizzled (V^T, m padded 0)
    __shared__ __align__(16) __hip_bfloat16 Pb[112 * 128];  // 28672 B swizzled (probs)
    __shared__ float biasL[507];
    __shared__ int   idnL[98];
    __shared__ int   nbL[98];

    const int tid  = threadIdx.x;
    const int lane = tid & 63;
    const int wv   = tid >> 6;
    const int widx = blockIdx.x >> 2;
    const int head = blockIdx.x & 3;
    const int co   = head * 32;
    const size_t base = (size_t)widx * 98 * 384;

    // ---- staging ----
    bf16x8_t zz = {};
    for (int e = tid; e < 448; e += 256) {        // K rows (8 bf16 per slot)
        int row = e >> 2, c8 = e & 3;
        if (row < 98) {
            *(bf16x8_t*)(&Kb[row][c8 * 8]) =
                *(const bf16x8_t*)(qkv + base + (size_t)row * 384 + 128 + co + c8 * 8);
        } else {
            *(bf16x8_t*)(&Kb[row][c8 * 8]) = zz;
        }
    }
    for (int e = tid; e < 448; e += 256) {        // V -> Vt transpose scatter (swizzled)
        int row = e >> 2, c8 = e & 3;
        if (row < 98) {
            bf16x8_t v = *(const bf16x8_t*)(qkv + base + (size_t)row * 384 + 256 + co + c8 * 8);
            #pragma unroll
            for (int j = 0; j < 8; ++j) Vt[SWZ(c8 * 8 + j, row)] = ((__hip_bfloat16*)&v)[j];
        }
    }
    for (int e = tid; e < 1024; e += 256) {       // Vt zero pad m in [98,128)
        int r = e >> 5, c = 96 + (e & 31);
        if (c >= 98) Vt[SWZ(r, c)] = __float2bfloat16(0.f);
    }
    for (int e = tid; e < 1792; e += 256) {       // Pb zero pad k in [112,128)
        int r = e >> 4, c = 112 + (e & 15);
        Pb[SWZ(r, c)] = __float2bfloat16(0.f);
    }
    for (int i = tid; i < 507; i += 256) biasL[i] = rel_bias[i * 4 + head];
    if (tid < 98) {                               // region id + linear bias base
        int n = tid;
        int dw = n / 49, r49 = n - dw * 49, hw = r49 / 7, ww2 = r49 - hw * 7;
        nbL[n] = dw * 169 + hw * 13 + ww2;
        int wloc = widx & 255;
        int dI = wloc >> 6, hI = (wloc >> 3) & 7, wI = wloc & 7;
        int d = dI * 2 + dw, h = hI * 7 + hw, w = wI * 7 + ww2;
        int di = (d < 6) ? 0 : (d < 7 ? 1 : 2);
        int hi = (h < 49) ? 0 : (h < 52 ? 1 : 2);
        int wi = (w < 49) ? 0 : (w < 52 ? 1 : 2);
        idnL[n] = di * 9 + hi * 3 + wi;
    }
    __syncthreads();

    const int lm = lane & 15, quad = lane >> 4;
    const float scale = 0.17677669529663687f;     // 32^-0.5

    // per-lane m-side constants (fixed across tM)
    int  mnb[7], mid[7];
    bool mok[7];
    #pragma unroll
    for (int tN = 0; tN < 7; ++tN) {
        int m = tN * 16 + lm;
        mok[tN] = (m < 98);
        mnb[tN] = mok[tN] ? nbL[m] : 0;
        mid[tN] = mok[tN] ? idnL[m] : -1;
    }

    // ---- QK^T + bias + mask + softmax (wave owns row-tiles wv, wv+4) ----
    for (int tM = wv; tM < 7; tM += 4) {
        int qrow = tM * 16 + lm;
        bf16x8_t afr = zz;
        if (qrow < 98)
            afr = *(const bf16x8_t*)(qkv + base + (size_t)qrow * 384 + co + quad * 8);
        f32x4_t acc[7];
        #pragma unroll
        for (int tN = 0; tN < 7; ++tN) {
            bf16x8_t bfr = *(const bf16x8_t*)(&Kb[tN * 16 + lm][quad * 8]);
            f32x4_t c0 = {0.f, 0.f, 0.f, 0.f};
            acc[tN] = __builtin_amdgcn_mfma_f32_16x16x32_bf16(afr, bfr, c0, 0, 0, 0);
        }
        // n-side constants for this row-tile
        int  nnb[4], nid[4];
        bool nok[4];
        #pragma unroll
        for (int rg = 0; rg < 4; ++rg) {
            int n = tM * 16 + quad * 4 + rg;
            nok[rg] = (n < 98);
            nnb[rg] = nok[rg] ? nbL[n] : 0;
            nid[rg] = nok[rg] ? idnL[n] : -2;
        }
        float sv[7][4];
        #pragma unroll
        for (int tN = 0; tN < 7; ++tN) {
            #pragma unroll
            for (int rg = 0; rg < 4; ++rg) {
                float s;
                if (nok[rg] && mok[tN]) {
                    s = acc[tN][rg] * scale + biasL[nnb[rg] - mnb[tN] + 253];
                    s += (nid[rg] == mid[tN]) ? 0.f : -100.f;
                } else {
                    s = -1e30f;
                }
                sv[tN][rg] = s;
            }
        }
        #pragma unroll
        for (int rg = 0; rg < 4; ++rg) {
            float mx = sv[0][rg];
            #pragma unroll
            for (int tN = 1; tN < 7; ++tN) mx = fmaxf(mx, sv[tN][rg]);
            mx = fmaxf(mx, __shfl_xor(mx, 1));
            mx = fmaxf(mx, __shfl_xor(mx, 2));
            mx = fmaxf(mx, __shfl_xor(mx, 4));
            mx = fmaxf(mx, __shfl_xor(mx, 8));
            float p[7], sum = 0.f;
            #pragma unroll
            for (int tN = 0; tN < 7; ++tN) { p[tN] = __expf(sv[tN][rg] - mx); sum += p[tN]; }
            sum += __shfl_xor(sum, 1);
            sum += __shfl_xor(sum, 2);
            sum += __shfl_xor(sum, 4);
            sum += __shfl_xor(sum, 8);
            float inv = 1.f / sum;
            int n = tM * 16 + quad * 4 + rg;
            #pragma unroll
            for (int tN = 0; tN < 7; ++tN)
                Pb[SWZ(n, tN * 16 + lm)] = __float2bfloat16(p[tN] * inv);
        }
    }
    __syncthreads();

    // ---- PV: out[n][c] = sum_m P[n][m] * V[m][c], K=128 (padded) ----
    for (int t = wv; t < 14; t += 4) {
        int tM = t >> 1, tN = t & 1;
        f32x4_t acc = {0.f, 0.f, 0.f, 0.f};
        #pragma unroll
        for (int s = 0; s < 4; ++s) {
            bf16x8_t afr = *(const bf16x8_t*)(&Pb[SWZ(tM * 16 + lm, s * 32 + quad * 8)]);
            bf16x8_t bfr = *(const bf16x8_t*)(&Vt[SWZ(tN * 16 + lm, s * 32 + quad * 8)]);
            acc = __builtin_amdgcn_mfma_f32_16x16x32_bf16(afr, bfr, acc, 0, 0, 0);
        }
        int m = tN * 16 + lm;
        #pragma unroll
        for (int rg = 0; rg < 4; ++rg) {
            int n = tM * 16 + quad * 4 + rg;
            if (n < 98)
                qkv[base + (size_t)n * 384 + co + m] = __float2bfloat16(acc[rg]);  // q-slice reuse
        }
    }
}

// ---------------- Kernel 3: proj GEMM (bf16 MFMA, v2) + window-reverse scatter + residual ----------------
__global__ __launch_bounds__(256, 3) void proj_kernel(
    const __hip_bfloat16* __restrict__ attn,    // qkv buffer, cols 0..127 hold attn out
    const __hip_bfloat16* __restrict__ proj_wb, // (128,128) bf16 (pre-converted)
    const float* __restrict__ proj_b,
    const float* __restrict__ x,
    float* __restrict__ x2)
{
    __shared__ __align__(16) __hip_bfloat16 Abf[64][136];   // 17408 B attn rows (bf16)
    __shared__ int dstL[64];

    const int tid  = threadIdx.x;
    const int lane = tid & 63;
    const int wv   = tid >> 6;
    const int rowbase = blockIdx.x * 64;

    if (tid < 64) dstL[tid] = token_spatial_index(rowbase + tid);

    // stage attn rows (already bf16): 64 rows x 16 bf16x8 slots
    #pragma unroll
    for (int i = 0; i < 4; ++i) {
        int e = tid + i * 256;
        int r = e >> 4, c8 = e & 15;
        *(bf16x8_t*)(&Abf[r][c8 * 8]) = *(const bf16x8_t*)(attn + (size_t)(rowbase + r) * 384 + c8 * 8);
    }
    __syncthreads();

    const int lm   = lane & 15;
    const int quad = lane >> 4;
    const int colbase = wv * 32;   // wave owns 32 of 128 out cols

    bf16x8_t afr[4][4];
    #pragma unroll
    for (int rt = 0; rt < 4; ++rt)
        #pragma unroll
        for (int s = 0; s < 4; ++s)
            afr[rt][s] = *(const bf16x8_t*)(&Abf[rt * 16 + lm][s * 32 + quad * 8]);

    // batch-load all 8 weight fragments (2 col-tiles x 4 K-slices), A-operand
    bf16x8_t wfr[2][4];
    #pragma unroll
    for (int cti = 0; cti < 2; ++cti) {
        int wcol = colbase + cti * 16 + lm;
        const __hip_bfloat16* wp = proj_wb + (size_t)wcol * 128 + quad * 8;
        #pragma unroll
        for (int s = 0; s < 4; ++s)
            wfr[cti][s] = *(const bf16x8_t*)(wp + s * 32);
    }

    #pragma unroll
    for (int cti = 0; cti < 2; ++cti) {
        int gcol4 = colbase + cti * 16 + quad * 4;
        float4 fb = *(const float4*)(proj_b + gcol4);
        f32x4_t a0 = {0.f,0.f,0.f,0.f}, a1 = {0.f,0.f,0.f,0.f};
        f32x4_t a2 = {0.f,0.f,0.f,0.f}, a3 = {0.f,0.f,0.f,0.f};
        #pragma unroll
        for (int s = 0; s < 4; ++s) {
            a0 = __builtin_amdgcn_mfma_f32_16x16x32_bf16(wfr[cti][s], afr[0][s], a0, 0, 0, 0);
            a1 = __builtin_amdgcn_mfma_f32_16x16x32_bf16(wfr[cti][s], afr[1][s], a1, 0, 0, 0);
            a2 = __builtin_amdgcn_mfma_f32_16x16x32_bf16(wfr[cti][s], afr[2][s], a2, 0, 0, 0);
            a3 = __builtin_amdgcn_mfma_f32_16x16x32_bf16(wfr[cti][s], afr[3][s], a3, 0, 0, 0);
        }
        f32x4_t ar[4] = {a0, a1, a2, a3};
        #pragma unroll
        for (int rt = 0; rt < 4; ++rt) {
            int dst = dstL[rt * 16 + lm];
            size_t off = (size_t)dst * 128 + gcol4;
            float4 xr = *(const float4*)(x + off);
            float4 res;
            res.x = ar[rt][0] + fb.x + xr.x;
            res.y = ar[rt][1] + fb.y + xr.y;
            res.z = ar[rt][2] + fb.z + xr.z;
            res.w = ar[rt][3] + fb.w + xr.w;
            *(float4*)(x2 + off) = res;
        }
    }
}

// ---------------- Kernel 3.5: convert MLP weights fp32 -> bf16 (into dead qkv region) ----------------
__global__ __launch_bounds__(256) void prep_weights(
    const float* __restrict__ fc1_w,   // (512,128) = 65536
    const float* __restrict__ fc2_w,   // (128,512) = 65536
    __hip_bfloat16* __restrict__ wb)   // [0..65535]=fc1, [65536..131071]=fc2
{
    int i = blockIdx.x * 256 + threadIdx.x;
    if (i < 65536)       wb[i] = __float2bfloat16(fc1_w[i]);
    else if (i < 131072) wb[i] = __float2bfloat16(fc2_w[i - 65536]);
}

// ---------------- Kernel 4: LN2 + fc1 + GELU + fc2 + residual (MFMA, MLP v6) ----------------
// v6 = v3 structure (erff GELU restored — R13 measured fast-GELU regression) with
// hidden processed in 4 chunks of 128 (was 2 of 256): Hbf halves to [64][136],
// LDS 51.2 -> 34.8 KB -> 4 blocks/CU (occupancy 30 -> ~45%). Same wave layout,
// batched loads, bank pattern (both row strides = 4 dwords mod 32).
__global__ __launch_bounds__(256, 4) void mlp_mfma_kernel(
    const float* __restrict__ x2,
    const float* __restrict__ g2,
    const float* __restrict__ b2,
    const __hip_bfloat16* __restrict__ fc1_wb,  // (512,128) bf16
    const __hip_bfloat16* __restrict__ fc2_wb,  // (128,512) bf16
    const float* __restrict__ fc1_b,
    const float* __restrict__ fc2_b,
    float* __restrict__ out)
{
    __shared__ __align__(16) __hip_bfloat16 Abf[64][136];   // 17408 B (LN output)
    __shared__ __align__(16) __hip_bfloat16 Hbf[64][136];   // 17408 B (hidden chunk of 128)

    const int tid  = threadIdx.x;
    const int lane = tid & 63;
    const int wv   = tid >> 6;
    const int rowbase = blockIdx.x * 64;

    // ---- LN2 fully in registers: 4 lanes per row, 32 elems each ----
    {
        int r = tid >> 2, part = tid & 3;
        const float* xp = x2 + (size_t)(rowbase + r) * 128 + part * 32;
        float v[32];
        float s = 0.f, ss = 0.f;
        #pragma unroll
        for (int j = 0; j < 8; ++j) {
            float4 f = *(const float4*)(xp + j * 4);
            v[j*4+0] = f.x; v[j*4+1] = f.y; v[j*4+2] = f.z; v[j*4+3] = f.w;
            s  += f.x + f.y + f.z + f.w;
            ss += f.x*f.x + f.y*f.y + f.z*f.z + f.w*f.w;
        }
        s += __shfl_xor(s, 1); ss += __shfl_xor(ss, 1);
        s += __shfl_xor(s, 2); ss += __shfl_xor(ss, 2);
        float m = s * (1.f / 128.f);
        float var = ss * (1.f / 128.f) - m * m;
        float rstd = rsqrtf(var + 1e-5f);
        #pragma unroll
        for (int j = 0; j < 8; ++j) {
            int k = part * 32 + j * 4;
            bf16x4 pk;
            pk.h[0] = __float2bfloat16((v[j*4+0] - m) * rstd * g2[k+0] + b2[k+0]);
            pk.h[1] = __float2bfloat16((v[j*4+1] - m) * rstd * g2[k+1] + b2[k+1]);
            pk.h[2] = __float2bfloat16((v[j*4+2] - m) * rstd * g2[k+2] + b2[k+2]);
            pk.h[3] = __float2bfloat16((v[j*4+3] - m) * rstd * g2[k+3] + b2[k+3]);
            *(bf16x4*)(&Abf[r][k]) = pk;
        }
    }
    __syncthreads();

    const int lm   = lane & 15;
    const int quad = lane >> 4;

    // fc2 persistent accumulators: 64 rows x 32 out cols per wave
    f32x4_t acc2[2][4];
    #pragma unroll
    for (int ct = 0; ct < 2; ++ct)
        #pragma unroll
        for (int rt = 0; rt < 4; ++rt)
            acc2[ct][rt] = f32x4_t{0.f, 0.f, 0.f, 0.f};

    for (int c = 0; c < 4; ++c) {
        // ---- fc1 + GELU for hidden chunk c (128 cols); wave owns 32 cols ----
        {
            // activation fragments: all 4 row-tiles (reloaded per chunk to bound VGPRs)
            bf16x8_t afr[4][4];
            #pragma unroll
            for (int rt = 0; rt < 4; ++rt)
                #pragma unroll
                for (int s = 0; s < 4; ++s)
                    afr[rt][s] = *(const bf16x8_t*)(&Abf[rt * 16 + lm][s * 32 + quad * 8]);

            // batch-load 8 weight fragments (2 col-tiles x 4 K-slices)
            bf16x8_t wfr[2][4];
            #pragma unroll
            for (int cti = 0; cti < 2; ++cti) {
                int hcol = c * 128 + wv * 32 + cti * 16 + lm;
                const __hip_bfloat16* wp = fc1_wb + (size_t)hcol * 128 + quad * 8;
                #pragma unroll
                for (int s = 0; s < 4; ++s)
                    wfr[cti][s] = *(const bf16x8_t*)(wp + s * 32);
            }
            #pragma unroll
            for (int cti = 0; cti < 2; ++cti) {
                int hcol = c * 128 + wv * 32 + cti * 16 + lm;
                float bb = fc1_b[hcol];
                f32x4_t a0 = {0.f,0.f,0.f,0.f}, a1 = {0.f,0.f,0.f,0.f};
                f32x4_t a2 = {0.f,0.f,0.f,0.f}, a3 = {0.f,0.f,0.f,0.f};
                #pragma unroll
                for (int s = 0; s < 4; ++s) {
                    a0 = __builtin_amdgcn_mfma_f32_16x16x32_bf16(afr[0][s], wfr[cti][s], a0, 0, 0, 0);
                    a1 = __builtin_amdgcn_mfma_f32_16x16x32_bf16(afr[1][s], wfr[cti][s], a1, 0, 0, 0);
                    a2 = __builtin_amdgcn_mfma_f32_16x16x32_bf16(afr[2][s], wfr[cti][s], a2, 0, 0, 0);
                    a3 = __builtin_amdgcn_mfma_f32_16x16x32_bf16(afr[3][s], wfr[cti][s], a3, 0, 0, 0);
                }
                int lc = wv * 32 + cti * 16 + lm;
                #pragma unroll
                for (int rg = 0; rg < 4; ++rg) {
                    float v0 = a0[rg] + bb, v1 = a1[rg] + bb, v2 = a2[rg] + bb, v3 = a3[rg] + bb;
                    v0 = 0.5f * v0 * (1.f + erff(v0 * 0.70710678118654752f));
                    v1 = 0.5f * v1 * (1.f + erff(v1 * 0.70710678118654752f));
                    v2 = 0.5f * v2 * (1.f + erff(v2 * 0.70710678118654752f));
                    v3 = 0.5f * v3 * (1.f + erff(v3 * 0.70710678118654752f));
                    Hbf[ 0 + quad * 4 + rg][lc] = __float2bfloat16(v0);
                    Hbf[16 + quad * 4 + rg][lc] = __float2bfloat16(v1);
                    Hbf[32 + quad * 4 + rg][lc] = __float2bfloat16(v2);
                    Hbf[48 + quad * 4 + rg][lc] = __float2bfloat16(v3);
                }
            }
        }
        __syncthreads();

        // ---- fc2 partial: K = 128 (this chunk); wave owns 32 out cols ----
        {
            // batch-load 8 fc2 weight fragments (2 col-tiles x 4 K-slices)
            bf16x8_t wfr2[2][4];
            #pragma unroll
            for (int ct = 0; ct < 2; ++ct) {
                int ccol = wv * 32 + ct * 16 + lm;
                const __hip_bfloat16* wp = fc2_wb + (size_t)ccol * 512 + c * 128 + quad * 8;
                #pragma unroll
                for (int s = 0; s < 4; ++s)
                    wfr2[ct][s] = *(const bf16x8_t*)(wp + s * 32);
            }
            #pragma unroll
            for (int s = 0; s < 4; ++s) {
                bf16x8_t hfr[4];
                #pragma unroll
                for (int rt = 0; rt < 4; ++rt)
                    hfr[rt] = *(const bf16x8_t*)(&Hbf[rt * 16 + lm][s * 32 + quad * 8]);
                #pragma unroll
                for (int ct = 0; ct < 2; ++ct)
                    #pragma unroll
                    for (int rt = 0; rt < 4; ++rt)
                        acc2[ct][rt] = __builtin_amdgcn_mfma_f32_16x16x32_bf16(hfr[rt], wfr2[ct][s], acc2[ct][rt], 0, 0, 0);
            }
        }
        __syncthreads();
    }

    // ---- epilogue: bias + residual (re-read x2, exact fp32) ----
    #pragma unroll
    for (int ct = 0; ct < 2; ++ct) {
        int ccol = wv * 32 + ct * 16 + lm;
        float bb = fc2_b[ccol];
        #pragma unroll
        for (int rt = 0; rt < 4; ++rt) {
            #pragma unroll
            for (int rg = 0; rg < 4; ++rg) {
                int rr = rt * 16 + quad * 4 + rg;
                size_t off = (size_t)(rowbase + rr) * 128 + ccol;
                out[off] = acc2[ct][rt][rg] + bb + x2[off];
            }
        }
    }
}

extern "C" void kernel_launch(void* const* d_in, const int* in_sizes, int n_in,
                              void* d_out, int out_size, void* d_ws, size_t ws_size,
                              hipStream_t stream) {
    const float* x        = (const float*)d_in[0];
    const float* n1g      = (const float*)d_in[2];
    const float* n1b      = (const float*)d_in[3];
    const float* qkv_w    = (const float*)d_in[4];
    const float* qkv_b    = (const float*)d_in[5];
    const float* rel_bias = (const float*)d_in[6];
    const float* proj_w   = (const float*)d_in[7];
    const float* proj_b   = (const float*)d_in[8];
    const float* n2g      = (const float*)d_in[9];
    const float* n2b      = (const float*)d_in[10];
    const float* fc1_w    = (const float*)d_in[11];
    const float* fc1_b    = (const float*)d_in[12];
    const float* fc2_w    = (const float*)d_in[13];
    const float* fc2_b    = (const float*)d_in[14];
    float* out = (float*)d_out;

    __hip_bfloat16* qkv = (__hip_bfloat16*)d_ws;                       // 154,140,672 B (dead after proj)
    float* x2 = (float*)((char*)d_ws + 154140672);                     // 102,760,448 B
    __hip_bfloat16* wb  = (__hip_bfloat16*)d_ws;                       // overlaps dead qkv region (fc weights)
    __hip_bfloat16* fc1_wb = wb;
    __hip_bfloat16* fc2_wb = wb + 65536;

    // qkv/proj bf16 weights live in the head of d_out (only mlp writes d_out, last)
    __hip_bfloat16* qp_wb   = (__hip_bfloat16*)d_out;
    __hip_bfloat16* qkv_wb  = qp_wb;            // 49152
    __hip_bfloat16* proj_wb = qp_wb + 49152;    // 16384

    prep_qp_weights<<<256, 256, 0, stream>>>(qkv_w, proj_w, qp_wb);
    ln1_qkv_kernel<<<3136, 256, 0, stream>>>(x, n1g, n1b, qkv_wb, qkv_b, qkv);
    attn_mfma_kernel<<<8192, 256, 0, stream>>>(qkv, rel_bias);
    proj_kernel<<<3136, 256, 0, stream>>>(qkv, proj_wb, proj_b, x, x2);
    prep_weights<<<512, 256, 0, stream>>>(fc1_w, fc2_w, wb);           // after proj: qkv region dead
    mlp_mfma_kernel<<<3136, 256, 0, stream>>>(x2, n2g, n2b, fc1_wb, fc2_wb, fc1_b, fc2_b, out);
}

// Round 15
// 609.113 us; speedup vs baseline: 1.1567x; 1.1567x over previous
//
#include <hip/hip_runtime.h>
#include <hip/hip_bf16.h>

#define C_DIM 128
#define N_WIN 98
#define M_TOK 200704   // 8*8*56*56
#define B_WIN 2048

struct __align__(8) bf16x4 { __hip_bfloat16 h[4]; };

typedef __attribute__((ext_vector_type(8))) short bf16x8_t;   // 8 bf16 = 4 VGPRs
typedef __attribute__((ext_vector_type(4))) float f32x4_t;

// NOTE (R13 measured): tanh-form fast GELU (__expf + __fdividef) is SLOWER than
// libm erff here (171 -> 194us, VALUBusy 33 -> 39%). Keep erff.
// NOTE (R14 measured): __launch_bounds__(256,4) clamps VGPR to 64 -> acc spill to
// scratch (WRITE_SIZE 100->565MB, 171->278us). Keep min-waves at 3; let LDS set
// the occupancy limit.

// token index map used by BOTH gather (LN1) and scatter (proj epilogue):
// row = widx*98 + n  ->  flat spatial token index in the original layout
__device__ __forceinline__ int token_spatial_index(int row) {
    int widx = row / 98;
    int n = row - widx * 98;
    int b   = widx >> 8;          // / 256
    int rem = widx & 255;
    int dI = rem >> 6;            // D/2 = 4
    int hI = (rem >> 3) & 7;      // H/7 = 8
    int wI = rem & 7;             // W/7 = 8
    int dw = n / 49;
    int r49 = n - dw * 49;
    int hw = r49 / 7;
    int ww = r49 - hw * 7;
    int d = dI * 2 + dw;          // shifted-frame coords
    int h = hI * 7 + hw;
    int w = wI * 7 + ww;
    d = (d + 1) & 7;              // shifted[i] = orig[(i+1)%8]  (roll -1)
    h += 3; if (h >= 56) h -= 56; // roll -3
    w += 3; if (w >= 56) w -= 56;
    return ((b * 8 + d) * 56 + h) * 56 + w;
}

// ---------------- Kernel 0: convert qkv_w + proj_w fp32 -> bf16 (into d_out head) ----------------
__global__ __launch_bounds__(256) void prep_qp_weights(
    const float* __restrict__ qkv_w,    // (384,128) = 49152
    const float* __restrict__ proj_w,   // (128,128) = 16384
    __hip_bfloat16* __restrict__ qp)    // [0..49151]=qkv_w, [49152..65535]=proj_w
{
    int i = blockIdx.x * 256 + threadIdx.x;
    if (i < 49152)      qp[i] = __float2bfloat16(qkv_w[i]);
    else if (i < 65536) qp[i] = __float2bfloat16(proj_w[i - 49152]);
}

// ---------------- Kernel 1: LN1 + window gather + QKV GEMM (bf16 MFMA, v2) ----------------
__global__ __launch_bounds__(256, 3) void ln1_qkv_kernel(
    const float* __restrict__ x,
    const float* __restrict__ g1,
    const float* __restrict__ b1,
    const __hip_bfloat16* __restrict__ qkv_wb,  // (384,128) bf16 (pre-converted)
    const float* __restrict__ qkv_b,            // (384,)
    __hip_bfloat16* __restrict__ qkv_out)       // (200704,384) bf16 scratch
{
    __shared__ __align__(16) __hip_bfloat16 Abf[64][136];   // 17408 B LN output
    __shared__ int srcL[64];

    const int tid  = threadIdx.x;
    const int lane = tid & 63;
    const int wv   = tid >> 6;
    const int rowbase = blockIdx.x * 64;

    if (tid < 64) srcL[tid] = token_spatial_index(rowbase + tid);
    __syncthreads();

    // ---- gather + LayerNorm, fully in registers ----
    {
        int r = tid >> 2, part = tid & 3;            // 4 lanes per row, 32 elems each
        const float* xp = x + (size_t)srcL[r] * 128 + part * 32;
        float v[32];
        float s = 0.f, ss = 0.f;
        #pragma unroll
        for (int j = 0; j < 8; ++j) {
            float4 f = *(const float4*)(xp + j * 4);
            v[j*4+0] = f.x; v[j*4+1] = f.y; v[j*4+2] = f.z; v[j*4+3] = f.w;
            s  += f.x + f.y + f.z + f.w;
            ss += f.x*f.x + f.y*f.y + f.z*f.z + f.w*f.w;
        }
        s += __shfl_xor(s, 1); ss += __shfl_xor(ss, 1);
        s += __shfl_xor(s, 2); ss += __shfl_xor(ss, 2);
        float m = s * (1.f / 128.f);
        float var = ss * (1.f / 128.f) - m * m;
        float rstd = rsqrtf(var + 1e-5f);
        #pragma unroll
        for (int j = 0; j < 8; ++j) {
            int k = part * 32 + j * 4;
            bf16x4 pk;
            pk.h[0] = __float2bfloat16((v[j*4+0] - m) * rstd * g1[k+0] + b1[k+0]);
            pk.h[1] = __float2bfloat16((v[j*4+1] - m) * rstd * g1[k+1] + b1[k+1]);
            pk.h[2] = __float2bfloat16((v[j*4+2] - m) * rstd * g1[k+2] + b1[k+2]);
            pk.h[3] = __float2bfloat16((v[j*4+3] - m) * rstd * g1[k+3] + b1[k+3]);
            *(bf16x4*)(&Abf[r][k]) = pk;
        }
    }
    __syncthreads();

    const int lm   = lane & 15;
    const int quad = lane >> 4;
    const int colbase = wv * 96;    // wave owns 96 of 384 out cols

    // activation fragments: all 4 row-tiles (B-operand)
    bf16x8_t afr[4][4];
    #pragma unroll
    for (int rt = 0; rt < 4; ++rt)
        #pragma unroll
        for (int s = 0; s < 4; ++s)
            afr[rt][s] = *(const bf16x8_t*)(&Abf[rt * 16 + lm][s * 32 + quad * 8]);

    #pragma unroll
    for (int ctb = 0; ctb < 3; ++ctb) {
        // batch-load 8 weight fragments (2 col-tiles x 4 K-slices), A-operand
        bf16x8_t wfr[2][4];
        #pragma unroll
        for (int cti = 0; cti < 2; ++cti) {
            int wcol = colbase + (ctb * 2 + cti) * 16 + lm;        // A-row = out col
            const __hip_bfloat16* wp = qkv_wb + (size_t)wcol * 128 + quad * 8;
            #pragma unroll
            for (int s = 0; s < 4; ++s)
                wfr[cti][s] = *(const bf16x8_t*)(wp + s * 32);
        }
        #pragma unroll
        for (int cti = 0; cti < 2; ++cti) {
            int gcol4 = colbase + (ctb * 2 + cti) * 16 + quad * 4; // lane's 4 out cols
            float4 fb = *(const float4*)(qkv_b + gcol4);
            f32x4_t a0 = {0.f,0.f,0.f,0.f}, a1 = {0.f,0.f,0.f,0.f};
            f32x4_t a2 = {0.f,0.f,0.f,0.f}, a3 = {0.f,0.f,0.f,0.f};
            #pragma unroll
            for (int s = 0; s < 4; ++s) {
                a0 = __builtin_amdgcn_mfma_f32_16x16x32_bf16(wfr[cti][s], afr[0][s], a0, 0, 0, 0);
                a1 = __builtin_amdgcn_mfma_f32_16x16x32_bf16(wfr[cti][s], afr[1][s], a1, 0, 0, 0);
                a2 = __builtin_amdgcn_mfma_f32_16x16x32_bf16(wfr[cti][s], afr[2][s], a2, 0, 0, 0);
                a3 = __builtin_amdgcn_mfma_f32_16x16x32_bf16(wfr[cti][s], afr[3][s], a3, 0, 0, 0);
            }
            // lane: token row rt*16+lm, out cols gcol4..gcol4+3 -> packed bf16x4 store
            bf16x4 pk;
            pk.h[0] = __float2bfloat16(a0[0] + fb.x);
            pk.h[1] = __float2bfloat16(a0[1] + fb.y);
            pk.h[2] = __float2bfloat16(a0[2] + fb.z);
            pk.h[3] = __float2bfloat16(a0[3] + fb.w);
            *(bf16x4*)(qkv_out + (size_t)(rowbase +  0 + lm) * 384 + gcol4) = pk;
            pk.h[0] = __float2bfloat16(a1[0] + fb.x);
            pk.h[1] = __float2bfloat16(a1[1] + fb.y);
            pk.h[2] = __float2bfloat16(a1[2] + fb.z);
            pk.h[3] = __float2bfloat16(a1[3] + fb.w);
            *(bf16x4*)(qkv_out + (size_t)(rowbase + 16 + lm) * 384 + gcol4) = pk;
            pk.h[0] = __float2bfloat16(a2[0] + fb.x);
            pk.h[1] = __float2bfloat16(a2[1] + fb.y);
            pk.h[2] = __float2bfloat16(a2[2] + fb.z);
            pk.h[3] = __float2bfloat16(a2[3] + fb.w);
            *(bf16x4*)(qkv_out + (size_t)(rowbase + 32 + lm) * 384 + gcol4) = pk;
            pk.h[0] = __float2bfloat16(a3[0] + fb.x);
            pk.h[1] = __float2bfloat16(a3[1] + fb.y);
            pk.h[2] = __float2bfloat16(a3[2] + fb.z);
            pk.h[3] = __float2bfloat16(a3[3] + fb.w);
            *(bf16x4*)(qkv_out + (size_t)(rowbase + 48 + lm) * 384 + gcol4) = pk;
        }
    }
}

// ---------------- Kernel 2: attention per (window, head), MFMA (v2, unchanged) ----------------
#define SWZ(r, c) (((r) * 128) + ((c) ^ (((r) & 7) << 3)))

__global__ __launch_bounds__(256) void attn_mfma_kernel(
    __hip_bfloat16* __restrict__ qkv,           // (200704,384); out overwrites q-slice
    const float* __restrict__ rel_bias)         // (507,4)
{
    __shared__ __align__(16) __hip_bfloat16 Kb[112][40];    // 8960 B (rows padded w/ zeros)
    __shared__ __align__(16) __hip_bfloat16 Vt[32 * 128];   // 8192 B swizzled (V^T, m padded 0)
    __shared__ __align__(16) __hip_bfloat16 Pb[112 * 128];  // 28672 B swizzled (probs)
    __shared__ float biasL[507];
    __shared__ int   idnL[98];
    __shared__ int   nbL[98];

    const int tid  = threadIdx.x;
    const int lane = tid & 63;
    const int wv   = tid >> 6;
    const int widx = blockIdx.x >> 2;
    const int head = blockIdx.x & 3;
    const int co   = head * 32;
    const size_t base = (size_t)widx * 98 * 384;

    // ---- staging ----
    bf16x8_t zz = {};
    for (int e = tid; e < 448; e += 256) {        // K rows (8 bf16 per slot)
        int row = e >> 2, c8 = e & 3;
        if (row < 98) {
            *(bf16x8_t*)(&Kb[row][c8 * 8]) =
                *(const bf16x8_t*)(qkv + base + (size_t)row * 384 + 128 + co + c8 * 8);
        } else {
            *(bf16x8_t*)(&Kb[row][c8 * 8]) = zz;
        }
    }
    for (int e = tid; e < 448; e += 256) {        // V -> Vt transpose scatter (swizzled)
        int row = e >> 2, c8 = e & 3;
        if (row < 98) {
            bf16x8_t v = *(const bf16x8_t*)(qkv + base + (size_t)row * 384 + 256 + co + c8 * 8);
            #pragma unroll
            for (int j = 0; j < 8; ++j) Vt[SWZ(c8 * 8 + j, row)] = ((__hip_bfloat16*)&v)[j];
        }
    }
    for (int e = tid; e < 1024; e += 256) {       // Vt zero pad m in [98,128)
        int r = e >> 5, c = 96 + (e & 31);
        if (c >= 98) Vt[SWZ(r, c)] = __float2bfloat16(0.f);
    }
    for (int e = tid; e < 1792; e += 256) {       // Pb zero pad k in [112,128)
        int r = e >> 4, c = 112 + (e & 15);
        Pb[SWZ(r, c)] = __float2bfloat16(0.f);
    }
    for (int i = tid; i < 507; i += 256) biasL[i] = rel_bias[i * 4 + head];
    if (tid < 98) {                               // region id + linear bias base
        int n = tid;
        int dw = n / 49, r49 = n - dw * 49, hw = r49 / 7, ww2 = r49 - hw * 7;
        nbL[n] = dw * 169 + hw * 13 + ww2;
        int wloc = widx & 255;
        int dI = wloc >> 6, hI = (wloc >> 3) & 7, wI = wloc & 7;
        int d = dI * 2 + dw, h = hI * 7 + hw, w = wI * 7 + ww2;
        int di = (d < 6) ? 0 : (d < 7 ? 1 : 2);
        int hi = (h < 49) ? 0 : (h < 52 ? 1 : 2);
        int wi = (w < 49) ? 0 : (w < 52 ? 1 : 2);
        idnL[n] = di * 9 + hi * 3 + wi;
    }
    __syncthreads();

    const int lm = lane & 15, quad = lane >> 4;
    const float scale = 0.17677669529663687f;     // 32^-0.5

    // per-lane m-side constants (fixed across tM)
    int  mnb[7], mid[7];
    bool mok[7];
    #pragma unroll
    for (int tN = 0; tN < 7; ++tN) {
        int m = tN * 16 + lm;
        mok[tN] = (m < 98);
        mnb[tN] = mok[tN] ? nbL[m] : 0;
        mid[tN] = mok[tN] ? idnL[m] : -1;
    }

    // ---- QK^T + bias + mask + softmax (wave owns row-tiles wv, wv+4) ----
    for (int tM = wv; tM < 7; tM += 4) {
        int qrow = tM * 16 + lm;
        bf16x8_t afr = zz;
        if (qrow < 98)
            afr = *(const bf16x8_t*)(qkv + base + (size_t)qrow * 384 + co + quad * 8);
        f32x4_t acc[7];
        #pragma unroll
        for (int tN = 0; tN < 7; ++tN) {
            bf16x8_t bfr = *(const bf16x8_t*)(&Kb[tN * 16 + lm][quad * 8]);
            f32x4_t c0 = {0.f, 0.f, 0.f, 0.f};
            acc[tN] = __builtin_amdgcn_mfma_f32_16x16x32_bf16(afr, bfr, c0, 0, 0, 0);
        }
        // n-side constants for this row-tile
        int  nnb[4], nid[4];
        bool nok[4];
        #pragma unroll
        for (int rg = 0; rg < 4; ++rg) {
            int n = tM * 16 + quad * 4 + rg;
            nok[rg] = (n < 98);
            nnb[rg] = nok[rg] ? nbL[n] : 0;
            nid[rg] = nok[rg] ? idnL[n] : -2;
        }
        float sv[7][4];
        #pragma unroll
        for (int tN = 0; tN < 7; ++tN) {
            #pragma unroll
            for (int rg = 0; rg < 4; ++rg) {
                float s;
                if (nok[rg] && mok[tN]) {
                    s = acc[tN][rg] * scale + biasL[nnb[rg] - mnb[tN] + 253];
                    s += (nid[rg] == mid[tN]) ? 0.f : -100.f;
                } else {
                    s = -1e30f;
                }
                sv[tN][rg] = s;
            }
        }
        #pragma unroll
        for (int rg = 0; rg < 4; ++rg) {
            float mx = sv[0][rg];
            #pragma unroll
            for (int tN = 1; tN < 7; ++tN) mx = fmaxf(mx, sv[tN][rg]);
            mx = fmaxf(mx, __shfl_xor(mx, 1));
            mx = fmaxf(mx, __shfl_xor(mx, 2));
            mx = fmaxf(mx, __shfl_xor(mx, 4));
            mx = fmaxf(mx, __shfl_xor(mx, 8));
            float p[7], sum = 0.f;
            #pragma unroll
            for (int tN = 0; tN < 7; ++tN) { p[tN] = __expf(sv[tN][rg] - mx); sum += p[tN]; }
            sum += __shfl_xor(sum, 1);
            sum += __shfl_xor(sum, 2);
            sum += __shfl_xor(sum, 4);
            sum += __shfl_xor(sum, 8);
            float inv = 1.f / sum;
            int n = tM * 16 + quad * 4 + rg;
            #pragma unroll
            for (int tN = 0; tN < 7; ++tN)
                Pb[SWZ(n, tN * 16 + lm)] = __float2bfloat16(p[tN] * inv);
        }
    }
    __syncthreads();

    // ---- PV: out[n][c] = sum_m P[n][m] * V[m][c], K=128 (padded) ----
    for (int t = wv; t < 14; t += 4) {
        int tM = t >> 1, tN = t & 1;
        f32x4_t acc = {0.f, 0.f, 0.f, 0.f};
        #pragma unroll
        for (int s = 0; s < 4; ++s) {
            bf16x8_t afr = *(const bf16x8_t*)(&Pb[SWZ(tM * 16 + lm, s * 32 + quad * 8)]);
            bf16x8_t bfr = *(const bf16x8_t*)(&Vt[SWZ(tN * 16 + lm, s * 32 + quad * 8)]);
            acc = __builtin_amdgcn_mfma_f32_16x16x32_bf16(afr, bfr, acc, 0, 0, 0);
        }
        int m = tN * 16 + lm;
        #pragma unroll
        for (int rg = 0; rg < 4; ++rg) {
            int n = tM * 16 + quad * 4 + rg;
            if (n < 98)
                qkv[base + (size_t)n * 384 + co + m] = __float2bfloat16(acc[rg]);  // q-slice reuse
        }
    }
}

// ---------------- Kernel 3: proj GEMM (bf16 MFMA, v2) + window-reverse scatter + residual ----------------
__global__ __launch_bounds__(256, 3) void proj_kernel(
    const __hip_bfloat16* __restrict__ attn,    // qkv buffer, cols 0..127 hold attn out
    const __hip_bfloat16* __restrict__ proj_wb, // (128,128) bf16 (pre-converted)
    const float* __restrict__ proj_b,
    const float* __restrict__ x,
    float* __restrict__ x2)
{
    __shared__ __align__(16) __hip_bfloat16 Abf[64][136];   // 17408 B attn rows (bf16)
    __shared__ int dstL[64];

    const int tid  = threadIdx.x;
    const int lane = tid & 63;
    const int wv   = tid >> 6;
    const int rowbase = blockIdx.x * 64;

    if (tid < 64) dstL[tid] = token_spatial_index(rowbase + tid);

    // stage attn rows (already bf16): 64 rows x 16 bf16x8 slots
    #pragma unroll
    for (int i = 0; i < 4; ++i) {
        int e = tid + i * 256;
        int r = e >> 4, c8 = e & 15;
        *(bf16x8_t*)(&Abf[r][c8 * 8]) = *(const bf16x8_t*)(attn + (size_t)(rowbase + r) * 384 + c8 * 8);
    }
    __syncthreads();

    const int lm   = lane & 15;
    const int quad = lane >> 4;
    const int colbase = wv * 32;   // wave owns 32 of 128 out cols

    bf16x8_t afr[4][4];
    #pragma unroll
    for (int rt = 0; rt < 4; ++rt)
        #pragma unroll
        for (int s = 0; s < 4; ++s)
            afr[rt][s] = *(const bf16x8_t*)(&Abf[rt * 16 + lm][s * 32 + quad * 8]);

    // batch-load all 8 weight fragments (2 col-tiles x 4 K-slices), A-operand
    bf16x8_t wfr[2][4];
    #pragma unroll
    for (int cti = 0; cti < 2; ++cti) {
        int wcol = colbase + cti * 16 + lm;
        const __hip_bfloat16* wp = proj_wb + (size_t)wcol * 128 + quad * 8;
        #pragma unroll
        for (int s = 0; s < 4; ++s)
            wfr[cti][s] = *(const bf16x8_t*)(wp + s * 32);
    }

    #pragma unroll
    for (int cti = 0; cti < 2; ++cti) {
        int gcol4 = colbase + cti * 16 + quad * 4;
        float4 fb = *(const float4*)(proj_b + gcol4);
        f32x4_t a0 = {0.f,0.f,0.f,0.f}, a1 = {0.f,0.f,0.f,0.f};
        f32x4_t a2 = {0.f,0.f,0.f,0.f}, a3 = {0.f,0.f,0.f,0.f};
        #pragma unroll
        for (int s = 0; s < 4; ++s) {
            a0 = __builtin_amdgcn_mfma_f32_16x16x32_bf16(wfr[cti][s], afr[0][s], a0, 0, 0, 0);
            a1 = __builtin_amdgcn_mfma_f32_16x16x32_bf16(wfr[cti][s], afr[1][s], a1, 0, 0, 0);
            a2 = __builtin_amdgcn_mfma_f32_16x16x32_bf16(wfr[cti][s], afr[2][s], a2, 0, 0, 0);
            a3 = __builtin_amdgcn_mfma_f32_16x16x32_bf16(wfr[cti][s], afr[3][s], a3, 0, 0, 0);
        }
        f32x4_t ar[4] = {a0, a1, a2, a3};
        #pragma unroll
        for (int rt = 0; rt < 4; ++rt) {
            int dst = dstL[rt * 16 + lm];
            size_t off = (size_t)dst * 128 + gcol4;
            float4 xr = *(const float4*)(x + off);
            float4 res;
            res.x = ar[rt][0] + fb.x + xr.x;
            res.y = ar[rt][1] + fb.y + xr.y;
            res.z = ar[rt][2] + fb.z + xr.z;
            res.w = ar[rt][3] + fb.w + xr.w;
            *(float4*)(x2 + off) = res;
        }
    }
}

// ---------------- Kernel 3.5: convert MLP weights fp32 -> bf16 (into dead qkv region) ----------------
__global__ __launch_bounds__(256) void prep_weights(
    const float* __restrict__ fc1_w,   // (512,128) = 65536
    const float* __restrict__ fc2_w,   // (128,512) = 65536
    __hip_bfloat16* __restrict__ wb)   // [0..65535]=fc1, [65536..131071]=fc2
{
    int i = blockIdx.x * 256 + threadIdx.x;
    if (i < 65536)       wb[i] = __float2bfloat16(fc1_w[i]);
    else if (i < 131072) wb[i] = __float2bfloat16(fc2_w[i - 65536]);
}

// ---------------- Kernel 4: LN2 + fc1 + GELU + fc2 + residual (MFMA, MLP v7) ----------------
// v7 = v3 (erff, operand order, epilogue all identical) with ONLY the hidden
// chunking changed: 4 chunks of 128 (Hbf [64][136], LDS 51.2 -> 34.8 KB -> 4
// blocks/CU) and launch_bounds kept at (256,3) so the VGPR allocator is NOT
// clamped (R14: (256,4) forced VGPR 64 -> acc2 spilled -> 565MB scratch writes).
__global__ __launch_bounds__(256, 3) void mlp_mfma_kernel(
    const float* __restrict__ x2,
    const float* __restrict__ g2,
    const float* __restrict__ b2,
    const __hip_bfloat16* __restrict__ fc1_wb,  // (512,128) bf16
    const __hip_bfloat16* __restrict__ fc2_wb,  // (128,512) bf16
    const float* __restrict__ fc1_b,
    const float* __restrict__ fc2_b,
    float* __restrict__ out)
{
    __shared__ __align__(16) __hip_bfloat16 Abf[64][136];   // 17408 B (LN output)
    __shared__ __align__(16) __hip_bfloat16 Hbf[64][136];   // 17408 B (hidden chunk of 128)

    const int tid  = threadIdx.x;
    const int lane = tid & 63;
    const int wv   = tid >> 6;
    const int rowbase = blockIdx.x * 64;

    // ---- LN2 fully in registers: 4 lanes per row, 32 elems each ----
    {
        int r = tid >> 2, part = tid & 3;
        const float* xp = x2 + (size_t)(rowbase + r) * 128 + part * 32;
        float v[32];
        float s = 0.f, ss = 0.f;
        #pragma unroll
        for (int j = 0; j < 8; ++j) {
            float4 f = *(const float4*)(xp + j * 4);
            v[j*4+0] = f.x; v[j*4+1] = f.y; v[j*4+2] = f.z; v[j*4+3] = f.w;
            s  += f.x + f.y + f.z + f.w;
            ss += f.x*f.x + f.y*f.y + f.z*f.z + f.w*f.w;
        }
        s += __shfl_xor(s, 1); ss += __shfl_xor(ss, 1);
        s += __shfl_xor(s, 2); ss += __shfl_xor(ss, 2);
        float m = s * (1.f / 128.f);
        float var = ss * (1.f / 128.f) - m * m;
        float rstd = rsqrtf(var + 1e-5f);
        #pragma unroll
        for (int j = 0; j < 8; ++j) {
            int k = part * 32 + j * 4;
            bf16x4 pk;
            pk.h[0] = __float2bfloat16((v[j*4+0] - m) * rstd * g2[k+0] + b2[k+0]);
            pk.h[1] = __float2bfloat16((v[j*4+1] - m) * rstd * g2[k+1] + b2[k+1]);
            pk.h[2] = __float2bfloat16((v[j*4+2] - m) * rstd * g2[k+2] + b2[k+2]);
            pk.h[3] = __float2bfloat16((v[j*4+3] - m) * rstd * g2[k+3] + b2[k+3]);
            *(bf16x4*)(&Abf[r][k]) = pk;
        }
    }
    __syncthreads();

    const int lm   = lane & 15;
    const int quad = lane >> 4;

    // fc2 persistent accumulators: 64 rows x 32 out cols per wave
    f32x4_t acc2[2][4];
    #pragma unroll
    for (int ct = 0; ct < 2; ++ct)
        #pragma unroll
        for (int rt = 0; rt < 4; ++rt)
            acc2[ct][rt] = f32x4_t{0.f, 0.f, 0.f, 0.f};

    for (int c = 0; c < 4; ++c) {
        // ---- fc1 + GELU for hidden chunk c (128 cols); wave owns 32 cols ----
        {
            // activation fragments: all 4 row-tiles (reloaded per chunk to bound VGPRs)
            bf16x8_t afr[4][4];
            #pragma unroll
            for (int rt = 0; rt < 4; ++rt)
                #pragma unroll
                for (int s = 0; s < 4; ++s)
                    afr[rt][s] = *(const bf16x8_t*)(&Abf[rt * 16 + lm][s * 32 + quad * 8]);

            // batch-load 8 weight fragments (2 col-tiles x 4 K-slices)
            bf16x8_t wfr[2][4];
            #pragma unroll
            for (int cti = 0; cti < 2; ++cti) {
                int hcol = c * 128 + wv * 32 + cti * 16 + lm;
                const __hip_bfloat16* wp = fc1_wb + (size_t)hcol * 128 + quad * 8;
                #pragma unroll
                for (int s = 0; s < 4; ++s)
                    wfr[cti][s] = *(const bf16x8_t*)(wp + s * 32);
            }
            #pragma unroll
            for (int cti = 0; cti < 2; ++cti) {
                int hcol = c * 128 + wv * 32 + cti * 16 + lm;
                float bb = fc1_b[hcol];
                f32x4_t a0 = {0.f,0.f,0.f,0.f}, a1 = {0.f,0.f,0.f,0.f};
                f32x4_t a2 = {0.f,0.f,0.f,0.f}, a3 = {0.f,0.f,0.f,0.f};
                #pragma unroll
                for (int s = 0; s < 4; ++s) {
                    a0 = __builtin_amdgcn_mfma_f32_16x16x32_bf16(afr[0][s], wfr[cti][s], a0, 0, 0, 0);
                    a1 = __builtin_amdgcn_mfma_f32_16x16x32_bf16(afr[1][s], wfr[cti][s], a1, 0, 0, 0);
                    a2 = __builtin_amdgcn_mfma_f32_16x16x32_bf16(afr[2][s], wfr[cti][s], a2, 0, 0, 0);
                    a3 = __builtin_amdgcn_mfma_f32_16x16x32_bf16(afr[3][s], wfr[cti][s], a3, 0, 0, 0);
                }
                int lc = wv * 32 + cti * 16 + lm;
                #pragma unroll
                for (int rg = 0; rg < 4; ++rg) {
                    float v0 = a0[rg] + bb, v1 = a1[rg] + bb, v2 = a2[rg] + bb, v3 = a3[rg] + bb;
                    v0 = 0.5f * v0 * (1.f + erff(v0 * 0.70710678118654752f));
                    v1 = 0.5f * v1 * (1.f + erff(v1 * 0.70710678118654752f));
                    v2 = 0.5f * v2 * (1.f + erff(v2 * 0.70710678118654752f));
                    v3 = 0.5f * v3 * (1.f + erff(v3 * 0.70710678118654752f));
                    Hbf[ 0 + quad * 4 + rg][lc] = __float2bfloat16(v0);
                    Hbf[16 + quad * 4 + rg][lc] = __float2bfloat16(v1);
                    Hbf[32 + quad * 4 + rg][lc] = __float2bfloat16(v2);
                    Hbf[48 + quad * 4 + rg][lc] = __float2bfloat16(v3);
                }
            }
        }
        __syncthreads();

        // ---- fc2 partial: K = 128 (this chunk); wave owns 32 out cols ----
        {
            // batch-load 8 fc2 weight fragments (2 col-tiles x 4 K-slices)
            bf16x8_t wfr2[2][4];
            #pragma unroll
            for (int ct = 0; ct < 2; ++ct) {
                int ccol = wv * 32 + ct * 16 + lm;
                const __hip_bfloat16* wp = fc2_wb + (size_t)ccol * 512 + c * 128 + quad * 8;
                #pragma unroll
                for (int s = 0; s < 4; ++s)
                    wfr2[ct][s] = *(const bf16x8_t*)(wp + s * 32);
            }
            #pragma unroll
            for (int s = 0; s < 4; ++s) {
                bf16x8_t hfr[4];
                #pragma unroll
                for (int rt = 0; rt < 4; ++rt)
                    hfr[rt] = *(const bf16x8_t*)(&Hbf[rt * 16 + lm][s * 32 + quad * 8]);
                #pragma unroll
                for (int ct = 0; ct < 2; ++ct)
                    #pragma unroll
                    for (int rt = 0; rt < 4; ++rt)
                        acc2[ct][rt] = __builtin_amdgcn_mfma_f32_16x16x32_bf16(hfr[rt], wfr2[ct][s], acc2[ct][rt], 0, 0, 0);
            }
        }
        __syncthreads();
    }

    // ---- epilogue: bias + residual (re-read x2, exact fp32) ----
    #pragma unroll
    for (int ct = 0; ct < 2; ++ct) {
        int ccol = wv * 32 + ct * 16 + lm;
        float bb = fc2_b[ccol];
        #pragma unroll
        for (int rt = 0; rt < 4; ++rt) {
            #pragma unroll
            for (int rg = 0; rg < 4; ++rg) {
                int rr = rt * 16 + quad * 4 + rg;
                size_t off = (size_t)(rowbase + rr) * 128 + ccol;
                out[off] = acc2[ct][rt][rg] + bb + x2[off];
            }
        }
    }
}

extern "C" void kernel_launch(void* const* d_in, const int* in_sizes, int n_in,
                              void* d_out, int out_size, void* d_ws, size_t ws_size,
                              hipStream_t stream) {
    const float* x        = (const float*)d_in[0];
    const float* n1g      = (const float*)d_in[2];
    const float* n1b      = (const float*)d_in[3];
    const float* qkv_w    = (const float*)d_in[4];
    const float* qkv_b    = (const float*)d_in[5];
    const float* rel_bias = (const float*)d_in[6];
    const float* proj_w   = (const float*)d_in[7];
    const float* proj_b   = (const float*)d_in[8];
    const float* n2g      = (const float*)d_in[9];
    const float* n2b      = (const float*)d_in[10];
    const float* fc1_w    = (const float*)d_in[11];
    const float* fc1_b    = (const float*)d_in[12];
    const float* fc2_w    = (const float*)d_in[13];
    const float* fc2_b    = (const float*)d_in[14];
    float* out = (float*)d_out;

    __hip_bfloat16* qkv = (__hip_bfloat16*)d_ws;                       // 154,140,672 B (dead after proj)
    float* x2 = (float*)((char*)d_ws + 154140672);                     // 102,760,448 B
    __hip_bfloat16* wb  = (__hip_bfloat16*)d_ws;                       // overlaps dead qkv region (fc weights)
    __hip_bfloat16* fc1_wb = wb;
    __hip_bfloat16* fc2_wb = wb + 65536;

    // qkv/proj bf16 weights live in the head of d_out (only mlp writes d_out, last)
    __hip_bfloat16* qp_wb   = (__hip_bfloat16*)d_out;
    __hip_bfloat16* qkv_wb  = qp_wb;            // 49152
    __hip_bfloat16* proj_wb = qp_wb + 49152;    // 16384

    prep_qp_weights<<<256, 256, 0, stream>>>(qkv_w, proj_w, qp_wb);
    ln1_qkv_kernel<<<3136, 256, 0, stream>>>(x, n1g, n1b, qkv_wb, qkv_b, qkv);
    attn_mfma_kernel<<<8192, 256, 0, stream>>>(qkv, rel_bias);
    proj_kernel<<<3136, 256, 0, stream>>>(qkv, proj_wb, proj_b, x, x2);
    prep_weights<<<512, 256, 0, stream>>>(fc1_w, fc2_w, wb);           // after proj: qkv region dead
    mlp_mfma_kernel<<<3136, 256, 0, stream>>>(x2, n2g, n2b, fc1_wb, fc2_wb, fc1_b, fc2_b, out);
}